// Round 12
// baseline (511.072 us; speedup 1.0000x reference)
//
#include <hip/hip_runtime.h>
#include <math.h>

// B=32, R=16384, C=16, IC=16, OC=16, 3 routing iterations.
// x: (B,C,IC) fp32 [8192]; W: (R,C,OC,IC) fp32 [67108864 = 256 MB]; out: (B,C,OC) fp32.
//
// Algebra: logits are linear in v with the same u_hat each pass:
//   L2 = <u, v1>,  L3 = L2 + <u, v2> = <u, v1 + v2>
// so pass 3 is the SAME kernel as pass 2 fed with vs = v1 + v2 -> no L history.
//
// R12: contiguous-stream MFMA.  R3-R11 all fixed c per block, so each block
// sampled 1 KB per 16 KB of W (per-r = 16 KB, per-(r,c) = 1 KB); the 16
// c-siblings were read by 16 different blocks at uncorrelated times -> DRAM
// page thrash, ~2 TB/s effective (k_wsum, which tiles W densely, streams the
// same bytes at ~18 TB/s).  Now: block (bx, by) = rows [64bx,64bx+64) x
// c-half [8by, 8by+8), wave w <-> c = 8by+w.  Per 2-row chunk the block's
// DMA covers two 8 KB CONTIGUOUS runs.  Wave-private LDS FIFOs (ring-4),
// fragment-permuted global source, counted vmcnt(6) distance-3, and ZERO
// barriers (waves fully independent; vf/E/Z go direct to global).

typedef __attribute__((ext_vector_type(8)))  short short8;
typedef __attribute__((ext_vector_type(16))) float f32x16;

union FU { short8 s; unsigned int u[4]; };

typedef const __attribute__((address_space(1))) void GV;
typedef __attribute__((address_space(3))) void LV;

// Split two fp32 into packed bf16 (hi, lo) pairs: hi = RNE-bf16; lo covers
// the next 16 bits (round-half-up).  Product w*x reconstructed with 4 MFMA
// terms -> residual ~2^-16 relative.
__device__ __forceinline__ void splitpk(float a, float b,
                                        unsigned int& hp, unsigned int& lp) {
    unsigned int ua = __float_as_uint(a), ub = __float_as_uint(b);
    unsigned int ta = ua + 0x7FFFu + ((ua >> 16) & 1u);   // RNE to bf16
    unsigned int tb = ub + 0x7FFFu + ((ub >> 16) & 1u);
    hp = (ta >> 16) | (tb & 0xFFFF0000u);                 // (hi_b<<16)|hi_a
    float ha = __uint_as_float(ta & 0xFFFF0000u);
    float hb = __uint_as_float(tb & 0xFFFF0000u);
    unsigned int la = __float_as_uint(a - ha) + 0x8000u;  // round-half-up
    unsigned int lb = __float_as_uint(b - hb) + 0x8000u;
    lp = (la >> 16) | (lb & 0xFFFF0000u);
}

// ---------------------------------------------------------------------------
// K0: zero the accumulator region (wsum+E2+Z2+E3+Z3 = 21504 floats).
// ---------------------------------------------------------------------------
__global__ __launch_bounds__(256) void k_zero(float* __restrict__ ws) {
    ws[blockIdx.x * 256 + threadIdx.x] = 0.f;      // grid 84 x 256 = 21504
}

// ---------------------------------------------------------------------------
// K1: wsum[c,o,i] = sum_r W[r,c,o,i].  W = 16,777,216 float4s.
// ---------------------------------------------------------------------------
__global__ __launch_bounds__(256) void k_wsum(const float4* __restrict__ W4,
                                              float* __restrict__ wsum) {
    int gid = blockIdx.x * 256 + threadIdx.x;      // [0, 262144)
    float4 acc = {0.f, 0.f, 0.f, 0.f};
    int idx = gid;
    #pragma unroll
    for (int it = 0; it < 64; ++it) {              // 16777216 / 262144 = 64
        float4 w = W4[idx];
        acc.x += w.x; acc.y += w.y; acc.z += w.z; acc.w += w.w;
        idx += 262144;
    }
    int cls = gid & 1023;                          // (c,o,i4) within an r-block
    atomicAdd(&wsum[cls * 4 + 0], acc.x);
    atomicAdd(&wsum[cls * 4 + 1], acc.y);
    atomicAdd(&wsum[cls * 4 + 2], acc.z);
    atomicAdd(&wsum[cls * 4 + 3], acc.w);
}

// ---------------------------------------------------------------------------
// K2: s1 = (1/R) * wsum . x ;  v1 = squash(s1)  -> v1[b*256 + c*16 + o]
// ---------------------------------------------------------------------------
__global__ __launch_bounds__(256) void k_v1(const float* __restrict__ wsum,
                                            const float* __restrict__ x,
                                            float* __restrict__ v1) {
    int t = blockIdx.x * 256 + threadIdx.x;        // 0..8191
    int o = t & 15, c = (t >> 4) & 15, b = t >> 8;
    const float* xb = x + (b * 16 + c) * 16;
    const float* wr = wsum + (c * 16 + o) * 16;
    float s = 0.f;
    #pragma unroll
    for (int i = 0; i < 16; ++i) s += wr[i] * xb[i];
    s *= (1.0f / 16384.0f);
    float ns = s * s;
    #pragma unroll
    for (int d = 1; d < 16; d <<= 1) ns += __shfl_xor(ns, d);
    v1[t] = s * (sqrtf(ns) / (1.0f + ns));
}

// ---------------------------------------------------------------------------
// K4a: v2 = squash(E/Z); vs = v1 + v2   (input to pass 3)
// ---------------------------------------------------------------------------
__global__ __launch_bounds__(256) void k_vout_vs(const float* __restrict__ E,
                                                 const float* __restrict__ Z,
                                                 const float* __restrict__ v1,
                                                 float* __restrict__ vs) {
    int t = blockIdx.x * 256 + threadIdx.x;        // 0..8191
    float s = E[t] / Z[t >> 4];                    // t>>4 = b*16+c
    float ns = s * s;
    #pragma unroll
    for (int d = 1; d < 16; d <<= 1) ns += __shfl_xor(ns, d);
    vs[t] = v1[t] + s * (sqrtf(ns) / (1.0f + ns));
}

// ---------------------------------------------------------------------------
// K4b: out = squash(E/Z)
// ---------------------------------------------------------------------------
__global__ __launch_bounds__(256) void k_vout(const float* __restrict__ E,
                                              const float* __restrict__ Z,
                                              float* __restrict__ dst) {
    int t = blockIdx.x * 256 + threadIdx.x;        // 0..8191
    float s = E[t] / Z[t >> 4];
    float ns = s * s;
    #pragma unroll
    for (int d = 1; d < 16; d <<= 1) ns += __shfl_xor(ns, d);
    dst[t] = s * (sqrtf(ns) / (1.0f + ns));
}

// ---------------------------------------------------------------------------
// K3: MFMA routing pass, contiguous per-block W stream.
//   Block (bx, by): rows [64bx, 64bx+64) x c in [8by, 8by+8); wave w has
//   c = 8by + w.  32 chunks of 2 rows.  Per chunk per wave:
//   A (M=32 x K=16): lane m=l&31 -> (r'=m>>4, o=m&15); k-slice i=8*(l>>5)+j.
//   B (K=16 x N=32): lane n=b, chunk-invariant (x in regs).
//   C: col=lane&31=b; row-reg o = (reg&3)+4*hi+8*((reg>>2)&1), r'=reg>>3.
//   Lv[b,r'] = 8 in-lane FMAs + ONE shfl_xor(32); e = exp(Lv);
//   accE[reg] += e*u; accZ += e0+e1 (pair-dup -> l<32 emits).
// Staging: wave-private; STAGE(sl,cn) = 2 global_load_lds of 1 KB; LDS
// [sl][wv][n][lane] linear dest, fragment-permuted global src.  The block's
// 8 waves jointly cover two 8 KB contiguous runs per chunk.  vmcnt is
// per-wave -> NO barriers anywhere in the kernel.  Ring-4, distance-3,
// steady-state vmcnt(6), tail 4/2/0.  Epilogue: fold r', direct global
// atomics (each (b,c,o) once per wave; 256 adds/address across the grid).
// ---------------------------------------------------------------------------
__global__ __launch_bounds__(512)
void k_iter(const float* __restrict__ W,
            const float* __restrict__ x,
            const float* __restrict__ v,
            float* __restrict__ E,
            float* __restrict__ Z) {
    __shared__ float4 Wr[4 * 1024];                // 64 KB: 4 slots x 8 wv x 2 x 64

    int tid = threadIdx.x, wv = tid >> 6, l = tid & 63;
    int m  = l & 31;                               // A-row / b-col
    int hi = l >> 5;                               // k-slice select
    int c  = blockIdx.y * 8 + wv;                  // wave-private capsule
    int r0 = blockIdx.x * 64;

    // B-fragment (x), chunk-invariant: lane b=m, i = 8*hi + 0..7
    FU bh, bl;
    {
        const float4* xb = (const float4*)x + m * 64 + c * 4 + hi * 2;
        float4 x0 = xb[0], x1 = xb[1];
        splitpk(x0.x, x0.y, bh.u[0], bl.u[0]);
        splitpk(x0.z, x0.w, bh.u[1], bl.u[1]);
        splitpk(x1.x, x1.y, bh.u[2], bl.u[2]);
        splitpk(x1.z, x1.w, bh.u[3], bl.u[3]);
    }

    // v-fragment matching C rows: vf[reg] = v[b=m][c][o(reg)]  (v is L2-hot)
    float vf[16];
    #pragma unroll
    for (int reg = 0; reg < 16; ++reg) {
        int o = (reg & 3) + 4 * hi + 8 * ((reg >> 2) & 1);
        vf[reg] = v[m * 256 + c * 16 + o];
    }

    float accE[16];
    #pragma unroll
    for (int reg = 0; reg < 16; ++reg) accE[reg] = 0.f;
    float accZ = 0.f;

    // pin vmcnt=0 so the counted waits below are exact (x/v loads retired)
    asm volatile("s_waitcnt vmcnt(0)" ::: "memory");

    // per-lane fragment-permuted source base: row = r0 + (m>>4), then
    // f4 = row*1024 + c*64 + (m&15)*4 + hi*2; chunk cn advances 2 rows = 2048.
    const float4* Wsrc = (const float4*)W +
        ((size_t)(r0 + (m >> 4)) * 1024 + c * 64 + (m & 15) * 4 + hi * 2);

#define STAGE(sl, cn) {                                                        \
        const float4* s0 = Wsrc + (size_t)(cn) * 2048;                         \
        __builtin_amdgcn_global_load_lds((GV*)s0,                              \
            (LV*)&Wr[(sl) * 1024 + wv * 128], 16, 0, 0);                       \
        __builtin_amdgcn_global_load_lds((GV*)(s0 + 1),                        \
            (LV*)&Wr[(sl) * 1024 + wv * 128 + 64], 16, 0, 0);                  \
    }

    auto body = [&](int chunk) {
        int sb = (chunk & 3) * 1024 + wv * 128 + l;
        float4 ca = Wr[sb];                        // ds_read_b128, conflict-free
        float4 cb = Wr[sb + 64];

        FU ah, al;                                 // split W -> A (hi, lo)
        splitpk(ca.x, ca.y, ah.u[0], al.u[0]);
        splitpk(ca.z, ca.w, ah.u[1], al.u[1]);
        splitpk(cb.x, cb.y, ah.u[2], al.u[2]);
        splitpk(cb.z, cb.w, ah.u[3], al.u[3]);

        f32x16 cf;                                 // u = W.x, 4-term bf16 split
        #pragma unroll
        for (int i = 0; i < 16; ++i) cf[i] = 0.f;
        cf = __builtin_amdgcn_mfma_f32_32x32x16_bf16(al.s, bl.s, cf, 0, 0, 0);
        cf = __builtin_amdgcn_mfma_f32_32x32x16_bf16(ah.s, bl.s, cf, 0, 0, 0);
        cf = __builtin_amdgcn_mfma_f32_32x32x16_bf16(al.s, bh.s, cf, 0, 0, 0);
        cf = __builtin_amdgcn_mfma_f32_32x32x16_bf16(ah.s, bh.s, cf, 0, 0, 0);

        float Lp0 = 0.f, Lp1 = 0.f;                // Lv[b,r'] = sum_o u*v
        #pragma unroll
        for (int reg = 0; reg < 8; ++reg)  Lp0 += cf[reg] * vf[reg];
        #pragma unroll
        for (int reg = 8; reg < 16; ++reg) Lp1 += cf[reg] * vf[reg];
        float Lv0 = Lp0 + __shfl_xor(Lp0, 32);     // partner has other 8 o's
        float Lv1 = Lp1 + __shfl_xor(Lp1, 32);
        float e0 = __expf(Lv0), e1 = __expf(Lv1);
        accZ += e0 + e1;                           // pair-duplicated
        #pragma unroll
        for (int reg = 0; reg < 8; ++reg)  accE[reg] += e0 * cf[reg];
        #pragma unroll
        for (int reg = 8; reg < 16; ++reg) accE[reg] += e1 * cf[reg];
    };

    STAGE(0, 0); STAGE(1, 1); STAGE(2, 2);         // 6 issues (6 KB/wave) in flight

    #pragma unroll 2
    for (int chunk = 0; chunk < 29; ++chunk) {     // steady state: 32 chunks total
        STAGE((chunk + 3) & 3, chunk + 3);
        asm volatile("s_waitcnt vmcnt(6)" ::: "memory");
        body(chunk);
    }
    asm volatile("s_waitcnt vmcnt(4)" ::: "memory"); body(29);
    asm volatile("s_waitcnt vmcnt(2)" ::: "memory"); body(30);
    asm volatile("s_waitcnt vmcnt(0)" ::: "memory"); body(31);
#undef STAGE

    // epilogue: fold r' pairs (same o), one global atomic per (b, c, o)
    #pragma unroll
    for (int j = 0; j < 8; ++j) {
        int o = (j & 3) + 4 * hi + 8 * (j >> 2);
        atomicAdd(&E[m * 256 + c * 16 + o], accE[j] + accE[j + 8]);
    }
    if (l < 32) atomicAdd(&Z[m * 16 + c], accZ);
}

// ---------------------------------------------------------------------------
// launch
// ---------------------------------------------------------------------------
extern "C" void kernel_launch(void* const* d_in, const int* in_sizes, int n_in,
                              void* d_out, int out_size, void* d_ws, size_t ws_size,
                              hipStream_t stream) {
    const float* x = (const float*)d_in[0];        // 8192 floats
    const float* W = (const float*)d_in[1];        // 67108864 floats (256 MB)
    float* out = (float*)d_out;                    // 8192 floats
    float* ws = (float*)d_ws;

    float* wsum = ws + 0;          // 4096
    float* E2   = ws + 4096;       // 8192
    float* Z2   = ws + 12288;      // 512
    float* E3   = ws + 12800;      // 8192
    float* Z3   = ws + 20992;      // 512   (accumulated region ends at 21504)
    float* v1   = ws + 21504;      // 8192
    float* vs   = ws + 29696;      // 8192  (v1 + v2, input to pass 3)

    // zero accumulators with our own kernel
    k_zero<<<84, 256, 0, stream>>>(ws);            // 84*256 = 21504 floats

    // iter 1: uniform softmax -> v1 from Wsum (W pass 1)
    k_wsum<<<1024, 256, 0, stream>>>((const float4*)W, wsum);
    k_v1<<<32, 256, 0, stream>>>(wsum, x, v1);

    // iter 2 fused: L2 = <u, v1>, E2/Z2 accumulated in-pass (W pass 2)
    k_iter<<<dim3(256, 2), 512, 0, stream>>>(W, x, v1, E2, Z2);
    k_vout_vs<<<32, 256, 0, stream>>>(E2, Z2, v1, vs);   // vs = v1 + squash(E2/Z2)

    // iter 3 fused: L3 = <u, v1+v2> (linearity: no history buffer needed)
    k_iter<<<dim3(256, 2), 512, 0, stream>>>(W, x, vs, E3, Z3);
    k_vout<<<32, 256, 0, stream>>>(E3, Z3, out);         // out = squash(E3/Z3)
}

// Round 13
// 209.386 us; speedup vs baseline: 2.4408x; 2.4408x over previous
//
#include <hip/hip_runtime.h>
#include <math.h>

// B=32, R=16384, C=16, IC=16, OC=16, 3 routing iterations.
// x: (B,C,IC) fp32 [8192]; W: (R,C,OC,IC) fp32 [67108864 = 256 MB]; out: (B,C,OC) fp32.
//
// Algebra: logits are linear in v with the same u_hat each pass:
//   L2 = <u, v1>,  L3 = L2 + <u, v2> = <u, v1 + v2>
// so pass 3 is the SAME kernel as pass 2 fed with vs = v1 + v2 -> no L history.
//
// R13: R11 structure (grid (64,16), wave-private DMA FIFOs, zero main-loop
// barriers) with ring-2 LDS (36 KB) -> 4 blocks/CU: the ENTIRE 1024-block
// grid is co-resident, so all 16 c-slices of every W row are streamed
// concurrently (full-row aggregation in L2/L3 -- the R12 post-mortem showed
// this concurrency, not per-block contiguity, is what feeds DRAM densely).
// R12's (256,2) grid broke aggregation and halved residency: 234us, 733GB/s.

typedef __attribute__((ext_vector_type(8)))  short short8;
typedef __attribute__((ext_vector_type(16))) float f32x16;

union FU { short8 s; unsigned int u[4]; };

typedef const __attribute__((address_space(1))) void GV;
typedef __attribute__((address_space(3))) void LV;

// Split two fp32 into packed bf16 (hi, lo) pairs: hi = RNE-bf16; lo covers
// the next 16 bits (round-half-up).  Product w*x reconstructed with 4 MFMA
// terms -> residual ~2^-16 relative.
__device__ __forceinline__ void splitpk(float a, float b,
                                        unsigned int& hp, unsigned int& lp) {
    unsigned int ua = __float_as_uint(a), ub = __float_as_uint(b);
    unsigned int ta = ua + 0x7FFFu + ((ua >> 16) & 1u);   // RNE to bf16
    unsigned int tb = ub + 0x7FFFu + ((ub >> 16) & 1u);
    hp = (ta >> 16) | (tb & 0xFFFF0000u);                 // (hi_b<<16)|hi_a
    float ha = __uint_as_float(ta & 0xFFFF0000u);
    float hb = __uint_as_float(tb & 0xFFFF0000u);
    unsigned int la = __float_as_uint(a - ha) + 0x8000u;  // round-half-up
    unsigned int lb = __float_as_uint(b - hb) + 0x8000u;
    lp = (la >> 16) | (lb & 0xFFFF0000u);
}

// ---------------------------------------------------------------------------
// K0: zero the accumulator region (wsum+E2+Z2+E3+Z3 = 21504 floats).
// ---------------------------------------------------------------------------
__global__ __launch_bounds__(256) void k_zero(float* __restrict__ ws) {
    ws[blockIdx.x * 256 + threadIdx.x] = 0.f;      // grid 84 x 256 = 21504
}

// ---------------------------------------------------------------------------
// K1: wsum[c,o,i] = sum_r W[r,c,o,i].  W = 16,777,216 float4s.
// ---------------------------------------------------------------------------
__global__ __launch_bounds__(256) void k_wsum(const float4* __restrict__ W4,
                                              float* __restrict__ wsum) {
    int gid = blockIdx.x * 256 + threadIdx.x;      // [0, 262144)
    float4 acc = {0.f, 0.f, 0.f, 0.f};
    int idx = gid;
    #pragma unroll
    for (int it = 0; it < 64; ++it) {              // 16777216 / 262144 = 64
        float4 w = W4[idx];
        acc.x += w.x; acc.y += w.y; acc.z += w.z; acc.w += w.w;
        idx += 262144;
    }
    int cls = gid & 1023;                          // (c,o,i4) within an r-block
    atomicAdd(&wsum[cls * 4 + 0], acc.x);
    atomicAdd(&wsum[cls * 4 + 1], acc.y);
    atomicAdd(&wsum[cls * 4 + 2], acc.z);
    atomicAdd(&wsum[cls * 4 + 3], acc.w);
}

// ---------------------------------------------------------------------------
// K2: s1 = (1/R) * wsum . x ;  v1 = squash(s1)  -> v1[b*256 + c*16 + o]
// ---------------------------------------------------------------------------
__global__ __launch_bounds__(256) void k_v1(const float* __restrict__ wsum,
                                            const float* __restrict__ x,
                                            float* __restrict__ v1) {
    int t = blockIdx.x * 256 + threadIdx.x;        // 0..8191
    int o = t & 15, c = (t >> 4) & 15, b = t >> 8;
    const float* xb = x + (b * 16 + c) * 16;
    const float* wr = wsum + (c * 16 + o) * 16;
    float s = 0.f;
    #pragma unroll
    for (int i = 0; i < 16; ++i) s += wr[i] * xb[i];
    s *= (1.0f / 16384.0f);
    float ns = s * s;
    #pragma unroll
    for (int d = 1; d < 16; d <<= 1) ns += __shfl_xor(ns, d);
    v1[t] = s * (sqrtf(ns) / (1.0f + ns));
}

// ---------------------------------------------------------------------------
// K4a: v2 = squash(E/Z); vs = v1 + v2   (input to pass 3)
// ---------------------------------------------------------------------------
__global__ __launch_bounds__(256) void k_vout_vs(const float* __restrict__ E,
                                                 const float* __restrict__ Z,
                                                 const float* __restrict__ v1,
                                                 float* __restrict__ vs) {
    int t = blockIdx.x * 256 + threadIdx.x;        // 0..8191
    float s = E[t] / Z[t >> 4];                    // t>>4 = b*16+c
    float ns = s * s;
    #pragma unroll
    for (int d = 1; d < 16; d <<= 1) ns += __shfl_xor(ns, d);
    vs[t] = v1[t] + s * (sqrtf(ns) / (1.0f + ns));
}

// ---------------------------------------------------------------------------
// K4b: out = squash(E/Z)
// ---------------------------------------------------------------------------
__global__ __launch_bounds__(256) void k_vout(const float* __restrict__ E,
                                              const float* __restrict__ Z,
                                              float* __restrict__ dst) {
    int t = blockIdx.x * 256 + threadIdx.x;        // 0..8191
    float s = E[t] / Z[t >> 4];
    float ns = s * s;
    #pragma unroll
    for (int d = 1; d < 16; d <<= 1) ns += __shfl_xor(ns, d);
    dst[t] = s * (sqrtf(ns) / (1.0f + ns));
}

// ---------------------------------------------------------------------------
// K3: MFMA routing pass, wave-private ring-2 DMA pipeline (R11 + residency).
//   Block (bx, c): rows [256bx, 256bx+256) x capsule c; 16 chunks of 16 rows;
//   wave wv owns rows {chunk*16 + wv*2, +1}.  Per (wave, chunk):
//   A (M=32 x K=16): lane m=l&31 -> (r'=m>>4, o=m&15); k-slice i=8*(l>>5)+j.
//   B (K=16 x N=32): lane n=b, chunk-invariant (x in regs).
//   C: col=lane&31=b; row-reg o=(reg&3)+4*hi+8*((reg>>2)&1), r'=reg>>3
//   [layout verified R10].  Lv[b,r'] = 8 in-lane FMAs + ONE shfl_xor(32).
// Staging: wave-private LDS FIFO [slot][wv][n][lane], linear dest, fragment-
// permuted global src; vmcnt (per-wave) alone orders data-ready -> NO
// main-loop barriers.  Ring-2 ledger: prologue stages 0,1; iter k:
//   vmcnt(2) [k's loads landed; k+1's flying] -> ds_read -> lgkmcnt(0)
//   [slot safe to overwrite] -> STAGE(k&1, k+2) [k<=13] -> compute.
// LDS 36 KB -> 4 blocks/CU: the whole grid co-resident, all 16 c's of every
// row concurrently streamed (aggregation), 32 waves/CU.
// Epilogue: fold r', ds-atomics to E_lds, one global atomic per thread.
// ---------------------------------------------------------------------------
__global__ __launch_bounds__(512)
void k_iter(const float* __restrict__ W,
            const float* __restrict__ x,
            const float* __restrict__ v,
            float* __restrict__ E,
            float* __restrict__ Z) {
    __shared__ float4 Wr[2 * 1024];                // 32 KB: 2 slots x 8 wv x 2 x 64
    __shared__ float sV[512];                      // v[b][o] for this c
    __shared__ float E_lds[512];                   // block-level E[b][o]
    __shared__ float Z_lds[32];

    int c = blockIdx.y;
    int r0 = blockIdx.x * 256;
    int tid = threadIdx.x, wv = tid >> 6, l = tid & 63;
    int m  = l & 31;                               // A-row / b-col
    int hi = l >> 5;                               // k-slice select

    // stage v + zero the block reduction buffers
    { int b = tid >> 4, o = tid & 15;
      sV[tid] = v[b * 256 + c * 16 + o];
      E_lds[tid] = 0.f; }
    if (tid < 32) Z_lds[tid] = 0.f;

    // B-fragment (x), chunk-invariant: lane b=m, i = 8*hi + 0..7
    FU bh, bl;
    {
        const float4* xb = (const float4*)x + m * 64 + c * 4 + hi * 2;
        float4 x0 = xb[0], x1 = xb[1];
        splitpk(x0.x, x0.y, bh.u[0], bl.u[0]);
        splitpk(x0.z, x0.w, bh.u[1], bl.u[1]);
        splitpk(x1.x, x1.y, bh.u[2], bl.u[2]);
        splitpk(x1.z, x1.w, bh.u[3], bl.u[3]);
    }
    __syncthreads();                               // sV ready (written cross-lane)

    // v-fragment matching C rows: vf[reg] = v[b = m][o(reg)]
    float vf[16];
    #pragma unroll
    for (int reg = 0; reg < 16; ++reg) {
        int o = (reg & 3) + 4 * hi + 8 * ((reg >> 2) & 1);
        vf[reg] = sV[m * 16 + o];
    }

    float accE[16];
    #pragma unroll
    for (int reg = 0; reg < 16; ++reg) accE[reg] = 0.f;
    float accZ = 0.f;

    // pin vmcnt=0 so the counted waits below are exact (x/sV loads retired)
    asm volatile("s_waitcnt vmcnt(0)" ::: "memory");

    const float4* W4c = (const float4*)W + (size_t)c * 64;   // row r at +r*1024

    // STAGE: wave wv stages its OWN 2 rows of chunk cn into slot sl.
    // src (per-lane, fragment-permuted): row = r0 + cn*16 + wv*2 + (m>>4),
    //   f4 = (m&15)*4 + hi*2 + n;   dest (linear): [sl][wv][n][lane].
#define STAGE(sl, cn) {                                                        \
        const float4* s0 = W4c +                                               \
            (size_t)(r0 + (cn) * 16 + wv * 2 + (m >> 4)) * 1024 +              \
            (m & 15) * 4 + hi * 2;                                             \
        __builtin_amdgcn_global_load_lds((GV*)s0,                              \
            (LV*)&Wr[(sl) * 1024 + wv * 128], 16, 0, 0);                       \
        __builtin_amdgcn_global_load_lds((GV*)(s0 + 1),                        \
            (LV*)&Wr[(sl) * 1024 + wv * 128 + 64], 16, 0, 0);                  \
    }

    STAGE(0, 0); STAGE(1, 1);                      // 4 issues in flight

    #pragma unroll
    for (int chunk = 0; chunk < 16; ++chunk) {
        // retire THIS wave's loads for chunk k; k+1's stay in flight
        if (chunk < 15) asm volatile("s_waitcnt vmcnt(2)" ::: "memory");
        else            asm volatile("s_waitcnt vmcnt(0)" ::: "memory");

        int sb = (chunk & 1) * 1024 + wv * 128 + l;
        float4 ca = Wr[sb];                        // ds_read_b128, conflict-free
        float4 cb = Wr[sb + 64];

        // slot reuse safety: reads retired before the DMA refill below
        asm volatile("s_waitcnt lgkmcnt(0)" ::: "memory");
        __builtin_amdgcn_sched_barrier(0);
        if (chunk <= 13) STAGE(chunk & 1, chunk + 2);

        // split W -> A-fragments (hi, lo)
        FU ah, al;
        splitpk(ca.x, ca.y, ah.u[0], al.u[0]);
        splitpk(ca.z, ca.w, ah.u[1], al.u[1]);
        splitpk(cb.x, cb.y, ah.u[2], al.u[2]);
        splitpk(cb.z, cb.w, ah.u[3], al.u[3]);

        // u = W.x via 4-term bf16 split (smallest term first)
        f32x16 cf;
        #pragma unroll
        for (int i = 0; i < 16; ++i) cf[i] = 0.f;
        cf = __builtin_amdgcn_mfma_f32_32x32x16_bf16(al.s, bl.s, cf, 0, 0, 0);
        cf = __builtin_amdgcn_mfma_f32_32x32x16_bf16(ah.s, bl.s, cf, 0, 0, 0);
        cf = __builtin_amdgcn_mfma_f32_32x32x16_bf16(al.s, bh.s, cf, 0, 0, 0);
        cf = __builtin_amdgcn_mfma_f32_32x32x16_bf16(ah.s, bh.s, cf, 0, 0, 0);

        // softmax: Lv[b, r'] = sum_o u*v;  regs 0-7 are r'=0, 8-15 r'=1
        float Lp0 = 0.f, Lp1 = 0.f;
        #pragma unroll
        for (int reg = 0; reg < 8; ++reg)  Lp0 += cf[reg] * vf[reg];
        #pragma unroll
        for (int reg = 8; reg < 16; ++reg) Lp1 += cf[reg] * vf[reg];
        float Lv0 = Lp0 + __shfl_xor(Lp0, 32);     // partner has other 8 o's
        float Lv1 = Lp1 + __shfl_xor(Lp1, 32);
        float e0 = __expf(Lv0), e1 = __expf(Lv1);
        accZ += e0 + e1;                           // pair-duplicated (l<32 emits)
        #pragma unroll
        for (int reg = 0; reg < 8; ++reg)  accE[reg] += e0 * cf[reg];
        #pragma unroll
        for (int reg = 8; reg < 16; ++reg) accE[reg] += e1 * cf[reg];
    }
#undef STAGE

    // fold r' pairs (same o), reduce across waves via LDS atomics
    #pragma unroll
    for (int j = 0; j < 8; ++j) {
        int o = (j & 3) + 4 * hi + 8 * (j >> 2);
        atomicAdd(&E_lds[m * 16 + o], accE[j] + accE[j + 8]);
    }
    if (l < 32) atomicAdd(&Z_lds[m], accZ);
    __syncthreads();

    atomicAdd(&E[(tid >> 4) * 256 + c * 16 + (tid & 15)], E_lds[tid]);
    if (tid < 32) atomicAdd(&Z[tid * 16 + c], Z_lds[tid]);
}

// ---------------------------------------------------------------------------
// launch
// ---------------------------------------------------------------------------
extern "C" void kernel_launch(void* const* d_in, const int* in_sizes, int n_in,
                              void* d_out, int out_size, void* d_ws, size_t ws_size,
                              hipStream_t stream) {
    const float* x = (const float*)d_in[0];        // 8192 floats
    const float* W = (const float*)d_in[1];        // 67108864 floats (256 MB)
    float* out = (float*)d_out;                    // 8192 floats
    float* ws = (float*)d_ws;

    float* wsum = ws + 0;          // 4096
    float* E2   = ws + 4096;       // 8192
    float* Z2   = ws + 12288;      // 512
    float* E3   = ws + 12800;      // 8192
    float* Z3   = ws + 20992;      // 512   (accumulated region ends at 21504)
    float* v1   = ws + 21504;      // 8192
    float* vs   = ws + 29696;      // 8192  (v1 + v2, input to pass 3)

    // zero accumulators with our own kernel
    k_zero<<<84, 256, 0, stream>>>(ws);            // 84*256 = 21504 floats

    // iter 1: uniform softmax -> v1 from Wsum (W pass 1)
    k_wsum<<<1024, 256, 0, stream>>>((const float4*)W, wsum);
    k_v1<<<32, 256, 0, stream>>>(wsum, x, v1);

    // iter 2 fused: L2 = <u, v1>, E2/Z2 accumulated in-pass (W pass 2)
    k_iter<<<dim3(64, 16), 512, 0, stream>>>(W, x, v1, E2, Z2);
    k_vout_vs<<<32, 256, 0, stream>>>(E2, Z2, v1, vs);   // vs = v1 + squash(E2/Z2)

    // iter 3 fused: L3 = <u, v1+v2> (linearity: no history buffer needed)
    k_iter<<<dim3(64, 16), 512, 0, stream>>>(W, x, vs, E3, Z3);
    k_vout<<<32, 256, 0, stream>>>(E3, Z3, out);         // out = squash(E3/Z3)
}